// Round 1
// baseline (269.999 us; speedup 1.0000x reference)
//
#include <hip/hip_runtime.h>
#include <hip/hip_bf16.h>

#define EPSN 1e-12f
#define EPSL 1e-10f
#define KSPLIT 8

typedef __attribute__((ext_vector_type(8))) short short8;
typedef __attribute__((ext_vector_type(4))) float f32x4;

__device__ __forceinline__ short f2bf_rne(float f) {
  union { float f; unsigned u; } x; x.f = f;
  unsigned r = x.u + 0x7FFFu + ((x.u >> 16) & 1u);
  return (short)(r >> 16);
}

// Kernel 1: per-row prep. One wave per row (D=128, 2 elems/lane).
// Computes e = x / max(||x||_4, eps), lpT[d][row] = bf16(log(e+eps)),
// plp[row] = sum_d e*log_p, and zeroes S/v accumulators.
__global__ __launch_bounds__(256)
void prep_kernel(const float* __restrict__ emb, float* __restrict__ e,
                 unsigned short* __restrict__ lpT, float* __restrict__ plp,
                 float* __restrict__ S, float* __restrict__ v, int N) {
  int w = threadIdx.x >> 6, l = threadIdx.x & 63;
  int row = blockIdx.x * 4 + w;
  if (row >= N) return;
  const float* x = emb + (size_t)row * 128;
  float2 xv = *(const float2*)(x + 2 * l);
  float s4 = xv.x*xv.x*xv.x*xv.x + xv.y*xv.y*xv.y*xv.y;
  #pragma unroll
  for (int m = 1; m < 64; m <<= 1) s4 += __shfl_xor(s4, m);
  float denom = fmaxf(sqrtf(sqrtf(s4)), EPSN);
  float e0 = xv.x / denom, e1 = xv.y / denom;
  float lp0 = logf(e0 + EPSL), lp1 = logf(e1 + EPSL);
  e[(size_t)row * 128 + 2*l]     = e0;
  e[(size_t)row * 128 + 2*l + 1] = e1;
  lpT[(size_t)(2*l)     * N + row] = (unsigned short)f2bf_rne(lp0);
  lpT[(size_t)(2*l + 1) * N + row] = (unsigned short)f2bf_rne(lp1);
  float pl = e0 * lp0 + e1 * lp1;
  #pragma unroll
  for (int m = 1; m < 64; m <<= 1) pl += __shfl_xor(pl, m);
  if (l == 0) { plp[row] = pl; S[row] = 0.f; v[row] = 0.f; }
}

// Kernel 2: fused GEMM M = adj @ log_p with in-register fp32->bf16 convert,
// fused adj rowsum, and epilogue contraction v[i] += sum_d e[i,d]*M_part[i,d].
// Block = 4 waves x 32 rows = 128-row M-tile; grid.y = K-splits.
__global__ __launch_bounds__(256)
void gemm_kernel(const float* __restrict__ adj, const float* __restrict__ e,
                 const unsigned short* __restrict__ lpT,
                 float* __restrict__ S, float* __restrict__ v, int N) {
  int w = threadIdx.x >> 6, l = threadIdx.x & 63;
  int l16 = l & 15, lhi = l >> 4;
  int row0 = blockIdx.x * 128 + w * 32;
  int kr = N / KSPLIT;
  int k0 = blockIdx.y * kr, k1 = k0 + kr;

  f32x4 acc[2][8];
  #pragma unroll
  for (int i = 0; i < 2; ++i)
    #pragma unroll
    for (int j = 0; j < 8; ++j) acc[i][j] = (f32x4){0.f, 0.f, 0.f, 0.f};
  float sA[2] = {0.f, 0.f};

  const size_t rs0 = (size_t)(row0 + l16) * N;
  const size_t rs1 = (size_t)(row0 + 16 + l16) * N;

  for (int k = k0; k < k1; k += 32) {
    int koff = k + lhi * 8;
    short8 a[2];
    #pragma unroll
    for (int rt = 0; rt < 2; ++rt) {
      const float* ap = adj + (rt ? rs1 : rs0) + koff;
      float4 x0 = *(const float4*)ap;
      float4 x1 = *(const float4*)(ap + 4);
      sA[rt] += ((x0.x + x0.y) + (x0.z + x0.w)) + ((x1.x + x1.y) + (x1.z + x1.w));
      short8 t;
      t[0] = f2bf_rne(x0.x); t[1] = f2bf_rne(x0.y);
      t[2] = f2bf_rne(x0.z); t[3] = f2bf_rne(x0.w);
      t[4] = f2bf_rne(x1.x); t[5] = f2bf_rne(x1.y);
      t[6] = f2bf_rne(x1.z); t[7] = f2bf_rne(x1.w);
      a[rt] = t;
    }
    #pragma unroll
    for (int ct = 0; ct < 8; ++ct) {
      const unsigned short* bp = lpT + (size_t)(ct * 16 + l16) * N + koff;
      short8 b = *(const short8*)bp;
      acc[0][ct] = __builtin_amdgcn_mfma_f32_16x16x32_bf16(a[0], b, acc[0][ct], 0, 0, 0);
      acc[1][ct] = __builtin_amdgcn_mfma_f32_16x16x32_bf16(a[1], b, acc[1][ct], 0, 0, 0);
    }
  }

  // adj rowsum partials: lanes {l, l^16, l^32, l^48} cover one row's K-slice.
  #pragma unroll
  for (int rt = 0; rt < 2; ++rt) {
    float s = sA[rt];
    s += __shfl_xor(s, 16);
    s += __shfl_xor(s, 32);
    if (l < 16) atomicAdd(&S[row0 + rt * 16 + l], s);
  }

  // v[i] += sum_d e[i,d] * C_part[i,d]; C layout: col=lane&15, row=(lane>>4)*4+reg.
  #pragma unroll
  for (int rt = 0; rt < 2; ++rt) {
    #pragma unroll
    for (int r = 0; r < 4; ++r) {
      int row = row0 + rt * 16 + lhi * 4 + r;
      float p = 0.f;
      #pragma unroll
      for (int ct = 0; ct < 8; ++ct)
        p += e[(size_t)row * 128 + ct * 16 + l16] * acc[rt][ct][r];
      p += __shfl_xor(p, 1);
      p += __shfl_xor(p, 2);
      p += __shfl_xor(p, 4);
      p += __shfl_xor(p, 8);
      if (l16 == 0) atomicAdd(&v[row], p);
    }
  }
}

// Kernel 3: out = lambda * sum_i [ plp[i]*(S_i/max(S_i,eps)) - v[i]/max(S_i,eps) ]
__global__ __launch_bounds__(256)
void final_kernel(const float* __restrict__ plp, const float* __restrict__ S,
                  const float* __restrict__ v, const float* __restrict__ lam,
                  float* __restrict__ out, int N) {
  __shared__ float red[4];
  float acc = 0.f;
  for (int i = threadIdx.x; i < N; i += 256) {
    float s = S[i], d = fmaxf(s, EPSN);
    acc += plp[i] * (s / d) - v[i] / d;
  }
  #pragma unroll
  for (int m = 1; m < 64; m <<= 1) acc += __shfl_xor(acc, m);
  int w = threadIdx.x >> 6, l = threadIdx.x & 63;
  if (l == 0) red[w] = acc;
  __syncthreads();
  if (threadIdx.x == 0) out[0] = lam[0] * (((red[0] + red[1]) + (red[2] + red[3])));
}

extern "C" void kernel_launch(void* const* d_in, const int* in_sizes, int n_in,
                              void* d_out, int out_size, void* d_ws, size_t ws_size,
                              hipStream_t stream) {
  const float* emb = (const float*)d_in[0];
  const float* adj = (const float*)d_in[1];
  const float* lam = (const float*)d_in[2];
  int N = in_sizes[0] / 128;  // D = 128 per reference

  char* ws = (char*)d_ws;
  float* e            = (float*)ws;                                    // N*128 f32
  unsigned short* lpT = (unsigned short*)(ws + (size_t)N * 128 * 4);   // 128*N bf16 (transposed)
  float* plp          = (float*)(ws + (size_t)N * 128 * 6);            // N f32
  float* S            = plp + N;                                       // N f32
  float* v            = S + N;                                         // N f32

  prep_kernel<<<(N + 3) / 4, 256, 0, stream>>>(emb, e, lpT, plp, S, v, N);
  dim3 grid(N / 128, KSPLIT);
  gemm_kernel<<<grid, 256, 0, stream>>>(adj, e, lpT, S, v, N);
  final_kernel<<<1, 256, 0, stream>>>(plp, S, v, lam, (float*)d_out, N);
}

// Round 2
// 231.837 us; speedup vs baseline: 1.1646x; 1.1646x over previous
//
#include <hip/hip_runtime.h>
#include <hip/hip_bf16.h>

#define EPSN 1e-12f
#define EPSL 1e-10f
#define KSPLIT 16
#define KS 64

typedef __attribute__((ext_vector_type(8))) short short8;
typedef __attribute__((ext_vector_type(4))) float f32x4;

__device__ __forceinline__ unsigned short f2bf_rne(float f) {
  union { float f; unsigned u; } x; x.f = f;
  unsigned r = x.u + 0x7FFFu + ((x.u >> 16) & 1u);
  return (unsigned short)(r >> 16);
}

// Kernel 1: per-row prep. One wave per row (D=128, 2 elems/lane).
// e = x / max(||x||_4, eps)  (fp32, row-major)
// lpB = bf16(log(e+eps)) scattered into MFMA B-fragment order:
//   element (d, k): frag f = (k>>5)*8 + (d>>4), lane = (d&15) + 16*((k>>3)&3),
//   ushort index = f*512 + lane*8 + (k&7)   -> each frag is a contiguous 1KB block.
// plp[row] = sum_d e*log_p; zero S/v.
__global__ __launch_bounds__(256)
void prep_kernel(const float* __restrict__ emb, float* __restrict__ e,
                 unsigned short* __restrict__ lpB, float* __restrict__ plp,
                 float* __restrict__ S, float* __restrict__ v, int N) {
  int w = threadIdx.x >> 6, l = threadIdx.x & 63;
  int row = blockIdx.x * 4 + w;
  if (row >= N) return;
  const float* x = emb + (size_t)row * 128;
  float2 xv = *(const float2*)(x + 2 * l);
  float s4 = xv.x*xv.x*xv.x*xv.x + xv.y*xv.y*xv.y*xv.y;
  #pragma unroll
  for (int m = 1; m < 64; m <<= 1) s4 += __shfl_xor(s4, m);
  float denom = fmaxf(sqrtf(sqrtf(s4)), EPSN);
  float e0 = xv.x / denom, e1 = xv.y / denom;
  float lp0 = logf(e0 + EPSL), lp1 = logf(e1 + EPSL);
  e[(size_t)row * 128 + 2*l]     = e0;
  e[(size_t)row * 128 + 2*l + 1] = e1;
  // scatter into fragment order (k = row)
  int ksr = row >> 5, lhir = (row >> 3) & 3, jr = row & 7;
  int d0 = 2 * l, d1 = 2 * l + 1;
  lpB[((size_t)(ksr*8 + (d0>>4))*64 + (d0&15) + 16*lhir)*8 + jr] = f2bf_rne(lp0);
  lpB[((size_t)(ksr*8 + (d1>>4))*64 + (d1&15) + 16*lhir)*8 + jr] = f2bf_rne(lp1);
  float pl = e0 * lp0 + e1 * lp1;
  #pragma unroll
  for (int m = 1; m < 64; m <<= 1) pl += __shfl_xor(pl, m);
  if (l == 0) { plp[row] = pl; S[row] = 0.f; v[row] = 0.f; }
}

// Kernel 2: fused GEMM M = adj @ log_p, per-wave LDS-staged A (fp32->bf16,
// fused rowsum), fragment-order contiguous B, epilogue e-contraction.
// Block = 4 waves x 32 rows (wave-private tiles, NO block barriers).
__global__ __launch_bounds__(256)
void gemm_kernel(const float* __restrict__ adj, const float* __restrict__ e,
                 const unsigned short* __restrict__ lpB,
                 float* __restrict__ S, float* __restrict__ v, int N) {
  __shared__ unsigned short lds[4][32][64];  // per-wave 32x64 bf16 tile, XOR-swizzled
  int w = threadIdx.x >> 6, l = threadIdx.x & 63;
  int l16 = l & 15, lhi = l >> 4;
  int row0 = blockIdx.x * 128 + w * 32;
  int kr = N / KSPLIT;
  int k0 = blockIdx.y * kr;
  int nsteps = kr / KS;  // 12

  f32x4 acc[2][8];
  #pragma unroll
  for (int i = 0; i < 2; ++i)
    #pragma unroll
    for (int j = 0; j < 8; ++j) acc[i][j] = (f32x4){0.f, 0.f, 0.f, 0.f};
  float sAcc[8];
  #pragma unroll
  for (int j = 0; j < 8; ++j) sAcc[j] = 0.f;

  char* wb = (char*)&lds[w][0][0];
  // staging: instr j covers rows j*4+lhi, cols l16*4..+3 (contiguous 256B/row)
  const float* aBase = adj + (size_t)(row0 + lhi) * N + k0 + l16 * 4;

  float4 ra[8], rb[8];

#define LOADA(buf, s)                                            \
  {                                                              \
    const float* p_ = aBase + (s) * KS;                          \
    _Pragma("unroll")                                            \
    for (int j_ = 0; j_ < 8; ++j_)                               \
      buf[j_] = *(const float4*)(p_ + (size_t)j_ * 4 * N);       \
  }

#define PROCESSA(buf)                                            \
  {                                                              \
    _Pragma("unroll")                                            \
    for (int j_ = 0; j_ < 8; ++j_) {                             \
      float4 x_ = buf[j_];                                       \
      sAcc[j_] += (x_.x + x_.y) + (x_.z + x_.w);                 \
      int row_ = j_ * 4 + lhi;                                   \
      unsigned p0_ = (unsigned)f2bf_rne(x_.x) | ((unsigned)f2bf_rne(x_.y) << 16); \
      unsigned p1_ = (unsigned)f2bf_rne(x_.z) | ((unsigned)f2bf_rne(x_.w) << 16); \
      int cb_ = (l16 * 8) ^ ((row_ & 7) << 4);                   \
      *(uint2*)(wb + row_ * 128 + cb_) = make_uint2(p0_, p1_);   \
    }                                                            \
  }

#define MFMAP(s)                                                           \
  {                                                                        \
    int ksa_ = (k0 + (s) * KS) >> 5;                                       \
    _Pragma("unroll")                                                      \
    for (int ks_ = 0; ks_ < 2; ++ks_) {                                    \
      short8 bb_[8];                                                       \
      _Pragma("unroll")                                                    \
      for (int ct_ = 0; ct_ < 8; ++ct_)                                    \
        bb_[ct_] = *(const short8*)(lpB + ((size_t)(ksa_ + ks_) * 8 + ct_) * 512 + l * 8); \
      short8 af_[2];                                                       \
      _Pragma("unroll")                                                    \
      for (int rt_ = 0; rt_ < 2; ++rt_) {                                  \
        int row_ = rt_ * 16 + l16;                                         \
        int cb_ = (ks_ * 64 + lhi * 16) ^ ((row_ & 7) << 4);               \
        af_[rt_] = *(const short8*)(wb + row_ * 128 + cb_);                \
      }                                                                    \
      _Pragma("unroll")                                                    \
      for (int ct_ = 0; ct_ < 8; ++ct_) {                                  \
        acc[0][ct_] = __builtin_amdgcn_mfma_f32_16x16x32_bf16(af_[0], bb_[ct_], acc[0][ct_], 0, 0, 0); \
        acc[1][ct_] = __builtin_amdgcn_mfma_f32_16x16x32_bf16(af_[1], bb_[ct_], acc[1][ct_], 0, 0, 0); \
      }                                                                    \
    }                                                                      \
  }

  LOADA(ra, 0);
  for (int s = 0; s < nsteps; s += 2) {
    LOADA(rb, s + 1);
    PROCESSA(ra);
    MFMAP(s);
    if (s + 2 < nsteps) LOADA(ra, s + 2);
    PROCESSA(rb);
    MFMAP(s + 1);
  }

  // adj rowsum partials: sAcc[j] belongs to row j*4+lhi; reduce over l16 (16 lanes).
  #pragma unroll
  for (int j = 0; j < 8; ++j) {
    float s = sAcc[j];
    s += __shfl_xor(s, 1);
    s += __shfl_xor(s, 2);
    s += __shfl_xor(s, 4);
    s += __shfl_xor(s, 8);
    if (l16 == 0) atomicAdd(&S[row0 + j * 4 + lhi], s);
  }

  // v[i] += sum_d e[i,d] * C_part[i,d]; C layout: col=lane&15, row=(lane>>4)*4+reg.
  #pragma unroll
  for (int rt = 0; rt < 2; ++rt) {
    #pragma unroll
    for (int r = 0; r < 4; ++r) {
      int row = row0 + rt * 16 + lhi * 4 + r;
      float p = 0.f;
      #pragma unroll
      for (int ct = 0; ct < 8; ++ct)
        p += e[(size_t)row * 128 + ct * 16 + l16] * acc[rt][ct][r];
      p += __shfl_xor(p, 1);
      p += __shfl_xor(p, 2);
      p += __shfl_xor(p, 4);
      p += __shfl_xor(p, 8);
      if (l16 == 0) atomicAdd(&v[row], p);
    }
  }
}

// Kernel 3: out = lambda * sum_i [ plp[i]*(S_i/max(S_i,eps)) - v[i]/max(S_i,eps) ]
__global__ __launch_bounds__(256)
void final_kernel(const float* __restrict__ plp, const float* __restrict__ S,
                  const float* __restrict__ v, const float* __restrict__ lam,
                  float* __restrict__ out, int N) {
  __shared__ float red[4];
  float acc = 0.f;
  for (int i = threadIdx.x; i < N; i += 256) {
    float s = S[i], d = fmaxf(s, EPSN);
    acc += plp[i] * (s / d) - v[i] / d;
  }
  #pragma unroll
  for (int m = 1; m < 64; m <<= 1) acc += __shfl_xor(acc, m);
  int w = threadIdx.x >> 6, l = threadIdx.x & 63;
  if (l == 0) red[w] = acc;
  __syncthreads();
  if (threadIdx.x == 0) out[0] = lam[0] * (((red[0] + red[1]) + (red[2] + red[3])));
}

extern "C" void kernel_launch(void* const* d_in, const int* in_sizes, int n_in,
                              void* d_out, int out_size, void* d_ws, size_t ws_size,
                              hipStream_t stream) {
  const float* emb = (const float*)d_in[0];
  const float* adj = (const float*)d_in[1];
  const float* lam = (const float*)d_in[2];
  int N = in_sizes[0] / 128;  // D = 128 per reference

  char* ws = (char*)d_ws;
  float* e            = (float*)ws;                                 // N*128 f32
  unsigned short* lpB = (unsigned short*)(ws + (size_t)N * 512);    // N*128 bf16, fragment order
  float* plp          = (float*)(ws + (size_t)N * 768);             // N f32
  float* S            = plp + N;                                    // N f32
  float* v            = S + N;                                      // N f32

  prep_kernel<<<(N + 3) / 4, 256, 0, stream>>>(emb, e, lpB, plp, S, v, N);
  dim3 grid(N / 128, KSPLIT);
  gemm_kernel<<<grid, 256, 0, stream>>>(adj, e, lpB, S, v, N);
  final_kernel<<<1, 256, 0, stream>>>(plp, S, v, lam, (float*)d_out, N);
}

// Round 3
// 205.555 us; speedup vs baseline: 1.3135x; 1.1279x over previous
//
#include <hip/hip_runtime.h>
#include <hip/hip_bf16.h>

#define EPSN 1e-12f
#define EPSL 1e-10f
#define KSPLIT 64
#define KS 64

typedef __attribute__((ext_vector_type(8))) short short8;
typedef __attribute__((ext_vector_type(4))) float f32x4;

__device__ __forceinline__ unsigned short f2bf_rne(float f) {
  union { float f; unsigned u; } x; x.f = f;
  unsigned r = x.u + 0x7FFFu + ((x.u >> 16) & 1u);
  return (unsigned short)(r >> 16);
}

// Kernel 1: per-row prep. One wave per row (D=128, 2 elems/lane).
// e = x / max(||x||_4, eps)  (fp32, row-major)
// lpB = bf16(log(e+eps)) scattered into MFMA B-fragment order:
//   element (d, k): frag f = (k>>5)*8 + (d>>4), lane = (d&15) + 16*((k>>3)&3),
//   ushort index = f*512 + lane*8 + (k&7)  -> each frag is a contiguous 1KB block.
// plp[row] = sum_d e*log_p; zero S/v.
__global__ __launch_bounds__(256)
void prep_kernel(const float* __restrict__ emb, float* __restrict__ e,
                 unsigned short* __restrict__ lpB, float* __restrict__ plp,
                 float* __restrict__ S, float* __restrict__ v, int N) {
  int w = threadIdx.x >> 6, l = threadIdx.x & 63;
  int row = blockIdx.x * 4 + w;
  if (row >= N) return;
  const float* x = emb + (size_t)row * 128;
  float2 xv = *(const float2*)(x + 2 * l);
  float s4 = xv.x*xv.x*xv.x*xv.x + xv.y*xv.y*xv.y*xv.y;
  #pragma unroll
  for (int m = 1; m < 64; m <<= 1) s4 += __shfl_xor(s4, m);
  float denom = fmaxf(sqrtf(sqrtf(s4)), EPSN);
  float e0 = xv.x / denom, e1 = xv.y / denom;
  float lp0 = logf(e0 + EPSL), lp1 = logf(e1 + EPSL);
  e[(size_t)row * 128 + 2*l]     = e0;
  e[(size_t)row * 128 + 2*l + 1] = e1;
  int ksr = row >> 5, lhir = (row >> 3) & 3, jr = row & 7;
  int d0 = 2 * l, d1 = 2 * l + 1;
  lpB[((size_t)(ksr*8 + (d0>>4))*64 + (d0&15) + 16*lhir)*8 + jr] = f2bf_rne(lp0);
  lpB[((size_t)(ksr*8 + (d1>>4))*64 + (d1&15) + 16*lhir)*8 + jr] = f2bf_rne(lp1);
  float pl = e0 * lp0 + e1 * lp1;
  #pragma unroll
  for (int m = 1; m < 64; m <<= 1) pl += __shfl_xor(pl, m);
  if (l == 0) { plp[row] = pl; S[row] = 0.f; v[row] = 0.f; }
}

// Kernel 2: fused GEMM M = adj @ log_p.
// Block = 4 waves x 32 rows = 128-row M-tile; grid.y = KSPLIT (64) k-slices.
// B for the block's ENTIRE 192-k range staged to LDS once (48KB, frag-ordered,
// contiguous); K-loop: A-fragments loaded direct global->reg (2-deep prefetch),
// fp32->bf16 in-register, fused adj rowsum, epilogue e-contraction.
__global__ __launch_bounds__(256, 2)
void gemm_kernel(const float* __restrict__ adj, const float* __restrict__ e,
                 const unsigned short* __restrict__ lpB,
                 float* __restrict__ S, float* __restrict__ v, int N) {
  __shared__ unsigned short bsh[KS * 3 * 128];  // 192k x 128d bf16 = 48KB
  int w = threadIdx.x >> 6, l = threadIdx.x & 63;
  int l16 = l & 15, lhi = l >> 4;
  int wrow0 = blockIdx.x * 128 + w * 32;
  int kr = N / KSPLIT;          // 192
  int k0 = blockIdx.y * kr;
  int nsteps = kr / KS;         // 3

  // ---- stage B: 48KB contiguous (frag-major), 12KB per wave, reg-staged ----
  {
    const short8* gB = (const short8*)(lpB + (size_t)k0 * 128);
    short8* sB = (short8*)bsh;
    #pragma unroll
    for (int i = 0; i < 12; ++i) {
      int idx = (w * 12 + i) * 64 + l;
      sB[idx] = gB[idx];
    }
  }

  f32x4 acc[2][8];
  #pragma unroll
  for (int i = 0; i < 2; ++i)
    #pragma unroll
    for (int j = 0; j < 8; ++j) acc[i][j] = (f32x4){0.f, 0.f, 0.f, 0.f};
  float sAcc[2] = {0.f, 0.f};

  // A-fragment bases: lane (l16, lhi) reads row (wrow0 + rt*16 + l16),
  // k = k0 + s*64 + ks*32 + lhi*8 .. +7  (2x dwordx4)
  const float* rp0 = adj + (size_t)(wrow0 + l16) * N + k0 + lhi * 8;
  const float* rp1 = rp0 + (size_t)16 * N;

  float4 ra[2][2][2], rb[2][2][2];

#define LOADA(buf, s)                                                   \
  {                                                                     \
    _Pragma("unroll")                                                   \
    for (int rt_ = 0; rt_ < 2; ++rt_) {                                 \
      const float* bp_ = (rt_ ? rp1 : rp0) + (s) * KS;                  \
      _Pragma("unroll")                                                 \
      for (int ks_ = 0; ks_ < 2; ++ks_) {                               \
        buf[rt_][ks_][0] = *(const float4*)(bp_ + ks_ * 32);            \
        buf[rt_][ks_][1] = *(const float4*)(bp_ + ks_ * 32 + 4);        \
      }                                                                 \
    }                                                                   \
  }

#define STEP(buf, s)                                                    \
  {                                                                     \
    _Pragma("unroll")                                                   \
    for (int ks_ = 0; ks_ < 2; ++ks_) {                                 \
      short8 bb_[8];                                                    \
      _Pragma("unroll")                                                 \
      for (int ct_ = 0; ct_ < 8; ++ct_)                                 \
        bb_[ct_] = *((const short8*)bsh + ((size_t)(((s)*2 + ks_)*8 + ct_))*64 + l); \
      short8 af_[2];                                                    \
      _Pragma("unroll")                                                 \
      for (int rt_ = 0; rt_ < 2; ++rt_) {                               \
        float4 x0_ = buf[rt_][ks_][0], x1_ = buf[rt_][ks_][1];          \
        sAcc[rt_] += ((x0_.x + x0_.y) + (x0_.z + x0_.w)) +              \
                     ((x1_.x + x1_.y) + (x1_.z + x1_.w));               \
        short8 t_;                                                      \
        t_[0] = (short)f2bf_rne(x0_.x); t_[1] = (short)f2bf_rne(x0_.y); \
        t_[2] = (short)f2bf_rne(x0_.z); t_[3] = (short)f2bf_rne(x0_.w); \
        t_[4] = (short)f2bf_rne(x1_.x); t_[5] = (short)f2bf_rne(x1_.y); \
        t_[6] = (short)f2bf_rne(x1_.z); t_[7] = (short)f2bf_rne(x1_.w); \
        af_[rt_] = t_;                                                  \
      }                                                                 \
      _Pragma("unroll")                                                 \
      for (int ct_ = 0; ct_ < 8; ++ct_) {                               \
        acc[0][ct_] = __builtin_amdgcn_mfma_f32_16x16x32_bf16(af_[0], bb_[ct_], acc[0][ct_], 0, 0, 0); \
        acc[1][ct_] = __builtin_amdgcn_mfma_f32_16x16x32_bf16(af_[1], bb_[ct_], acc[1][ct_], 0, 0, 0); \
      }                                                                 \
    }                                                                   \
  }

  LOADA(ra, 0);
  __syncthreads();  // B staged (drains vmcnt incl. ra prefetch — prologue only)

  for (int s = 0; s < nsteps; s += 2) {
    if (s + 1 < nsteps) LOADA(rb, s + 1);
    STEP(ra, s);
    if (s + 2 < nsteps) LOADA(ra, s + 2);
    if (s + 1 < nsteps) STEP(rb, s + 1);
  }

  // adj rowsum partials: lane (l16,lhi) holds row (wrow0+rt*16+l16)'s lhi-slice.
  #pragma unroll
  for (int rt = 0; rt < 2; ++rt) {
    float s = sAcc[rt];
    s += __shfl_xor(s, 16);
    s += __shfl_xor(s, 32);
    if (l < 16) atomicAdd(&S[wrow0 + rt * 16 + l], s);
  }

  // v[i] += sum_d e[i,d] * C_part[i,d]; C layout: col=lane&15, row=(lane>>4)*4+reg.
  #pragma unroll
  for (int rt = 0; rt < 2; ++rt) {
    #pragma unroll
    for (int r = 0; r < 4; ++r) {
      int row = wrow0 + rt * 16 + lhi * 4 + r;
      float p = 0.f;
      #pragma unroll
      for (int ct = 0; ct < 8; ++ct)
        p += e[(size_t)row * 128 + ct * 16 + l16] * acc[rt][ct][r];
      p += __shfl_xor(p, 1);
      p += __shfl_xor(p, 2);
      p += __shfl_xor(p, 4);
      p += __shfl_xor(p, 8);
      if (l16 == 0) atomicAdd(&v[row], p);
    }
  }
}

// Kernel 3: out = lambda * sum_i [ plp[i]*(S_i/max(S_i,eps)) - v[i]/max(S_i,eps) ]
__global__ __launch_bounds__(1024)
void final_kernel(const float* __restrict__ plp, const float* __restrict__ S,
                  const float* __restrict__ v, const float* __restrict__ lam,
                  float* __restrict__ out, int N) {
  __shared__ float red[16];
  float acc = 0.f;
  for (int i = threadIdx.x; i < N; i += 1024) {
    float s = S[i], d = fmaxf(s, EPSN);
    acc += plp[i] * (s / d) - v[i] / d;
  }
  #pragma unroll
  for (int m = 1; m < 64; m <<= 1) acc += __shfl_xor(acc, m);
  int w = threadIdx.x >> 6, l = threadIdx.x & 63;
  if (l == 0) red[w] = acc;
  __syncthreads();
  if (threadIdx.x == 0) {
    float t = 0.f;
    #pragma unroll
    for (int i = 0; i < 16; ++i) t += red[i];
    out[0] = lam[0] * t;
  }
}

extern "C" void kernel_launch(void* const* d_in, const int* in_sizes, int n_in,
                              void* d_out, int out_size, void* d_ws, size_t ws_size,
                              hipStream_t stream) {
  const float* emb = (const float*)d_in[0];
  const float* adj = (const float*)d_in[1];
  const float* lam = (const float*)d_in[2];
  int N = in_sizes[0] / 128;  // D = 128 per reference

  char* ws = (char*)d_ws;
  float* e            = (float*)ws;                                 // N*128 f32
  unsigned short* lpB = (unsigned short*)(ws + (size_t)N * 512);    // N*128 bf16, fragment order
  float* plp          = (float*)(ws + (size_t)N * 768);             // N f32
  float* S            = plp + N;                                    // N f32
  float* v            = S + N;                                      // N f32

  prep_kernel<<<(N + 3) / 4, 256, 0, stream>>>(emb, e, lpB, plp, S, v, N);
  dim3 grid(N / 128, KSPLIT);
  gemm_kernel<<<grid, 256, 0, stream>>>(adj, e, lpB, S, v, N);
  final_kernel<<<1, 1024, 0, stream>>>(plp, S, v, lam, (float*)d_out, N);
}